// Round 1
// baseline (94667.554 us; speedup 1.0000x reference)
//
#include <hip/hip_runtime.h>
#include <cstdint>
#include <cstddef>

#define T_ 2048
#define N_ 64
#define L_ 300
#define V_ 35
#define E_ 256
#define H_ 512
#define KS_ 128

typedef __attribute__((ext_vector_type(8))) short short8;
typedef __attribute__((ext_vector_type(4))) float float4v;

struct Params {
    // inputs (setup_inputs order)
    const float *key, *values;
    const int *x_lens, *text;
    const float *emb_W;
    const float *W_ih1, *W_hh1, *b_ih1, *b_hh1;
    const float *W_ih2, *W_hh2, *b_ih2, *b_hh2;
    const float *W_ih3, *W_hh3, *b_ih3, *b_hh3;
    const float *b_out;
    // workspace
    unsigned short *Wpk1, *Wpk2, *Wpk3;  // MFMA-A-fragment-packed bf16 weights
    float *embproj;                      // [V_][2048] = emb_W @ W_ih1[:, :256]^T + b_ih1 + b_hh1
    float *b2, *b3;
    unsigned short *keyB, *valB;         // [n][t][k] bf16
    float *out;
};

__device__ __forceinline__ float b2f(unsigned short u) {
    unsigned int i = ((unsigned int)u) << 16;
    float f; __builtin_memcpy(&f, &i, 4); return f;
}
__device__ __forceinline__ unsigned short f2b(float f) {
    unsigned int i; __builtin_memcpy(&i, &f, 4);
    i += 0x7FFFu + ((i >> 16) & 1u);
    return (unsigned short)(i >> 16);
}
__device__ __forceinline__ float sigm(float x) { return 1.0f / (1.0f + __expf(-x)); }
__device__ __forceinline__ float tanh_(float x) {
    float e = __expf(2.0f * x);
    return 1.0f - 2.0f / (e + 1.0f);
}
__device__ __forceinline__ float wredmax(float v) {
#pragma unroll
    for (int o = 32; o > 0; o >>= 1) v = fmaxf(v, __shfl_down(v, o));
    return v;
}
__device__ __forceinline__ float wredsum(float v) {
#pragma unroll
    for (int o = 32; o > 0; o >>= 1) v += __shfl_down(v, o);
    return v;
}
__device__ __forceinline__ float dot8(short8 w8, float4v a, float4v b) {
    return b2f((unsigned short)w8[0]) * a[0] + b2f((unsigned short)w8[1]) * a[1]
         + b2f((unsigned short)w8[2]) * a[2] + b2f((unsigned short)w8[3]) * a[3]
         + b2f((unsigned short)w8[4]) * b[0] + b2f((unsigned short)w8[5]) * b[1]
         + b2f((unsigned short)w8[6]) * b[2] + b2f((unsigned short)w8[7]) * b[3];
}

// All per-n state lives here for the whole 300-step recurrence. ~54.6 KB.
struct Sh {
    unsigned short xc1[640];   // [ctx(128) || h1(512)]          K for LSTM1 (emb folded into embproj)
    unsigned short xc2[1024];  // [h1(512) || h2prev(512)]       K for LSTM2
    unsigned short xc3[640];   // [h2(512) || h3prev(128)]       K for LSTM3
    float g[2048];             // gate pre-activations
    float c1[512], c2[512], c3[128];
    float h3s[128];
    float ctxf[128];
    float att[2048];
    float b2[2048], b3[512];
    float red[32];
    float lsum[V_][8];
    float ctxp[32][129];       // +1 pad: 4-way-max bank conflicts on scatter
};

// GEMV via MFMA: A = packed weight tile (16 rows x 32 k per lane-set), B = x broadcast
// into all 16 columns (LDS broadcast read, lane-uniform per 16-lane group).
// Wpk layout: [jt][kt][lane(64)][8] with elem = W[jt*16 + (lane&15)][kt*32 + (lane>>4)*8 + e].
template <int NJT, int NKT>
__device__ __forceinline__ void gemv_mfma(const unsigned short* __restrict__ Wpk,
                                          const unsigned short* xc, float* g,
                                          int wv, int lane)
{
    const int q = lane >> 4;
    float4v acc[NJT];
#pragma unroll
    for (int s = 0; s < NJT; s++) acc[s] = (float4v){0.f, 0.f, 0.f, 0.f};
    const unsigned short* wb = Wpk + (size_t)(wv * NJT) * NKT * 512 + lane * 8;
    for (int kt = 0; kt < NKT; ++kt) {
        short8 b = *(const short8*)(xc + kt * 32 + q * 8);
        const unsigned short* wp = wb + (size_t)kt * 512;
#pragma unroll
        for (int s = 0; s < NJT; s++)
            acc[s] = __builtin_amdgcn_mfma_f32_16x16x32_bf16(
                *(const short8*)(wp + (size_t)s * NKT * 512), b, acc[s], 0, 0, 0);
    }
    // D: col = lane&15 (all cols identical), row = (lane>>4)*4 + r
    if ((lane & 15) == 0) {
#pragma unroll
        for (int s = 0; s < NJT; s++)
#pragma unroll
            for (int r = 0; r < 4; r++)
                g[(wv * NJT + s) * 16 + q * 4 + r] = acc[s][r];
    }
}

// One WG per batch element n: the full 300-step recurrence with ZERO grid syncs.
__global__ __launch_bounds__(1024) void decoder_main(Params p)
{
    __shared__ Sh sh;
    const int n = blockIdx.x;        // 0..63
    const int tid = threadIdx.x;     // 0..1023
    const int lane = tid & 63, wv = tid >> 6;
    const int len = p.x_lens[n];
    const int* textn = p.text + n * L_;
    float* const attnout = p.out + (size_t)N_ * L_ * V_ + (size_t)n * L_ * T_;

    // init: biases -> LDS, zero all recurrent state
    for (int i = tid; i < 2048; i += 1024) sh.b2[i] = p.b2[i];
    if (tid < 512) sh.b3[tid] = p.b3[tid];
    if (tid < 512) { sh.c1[tid] = 0.f; sh.c2[tid] = 0.f; }
    if (tid < 128) sh.c3[tid] = 0.f;
    if (tid < 640) sh.xc1[tid] = 0;                 // ctx0 + h1_0
    if (tid >= 512 && tid < 1024) sh.xc2[tid] = 0;  // h2_0
    if (tid < 128) sh.xc3[512 + tid] = 0;           // h3_0
    __syncthreads();

    for (int l = 0; l < L_; ++l) {
        // prefetch this step's embedding-projection rows (teacher-forced char)
        float ep0 = 0.f, ep1 = 0.f, ep2 = 0.f, ep3 = 0.f;
        {
            const int row = textn[l];
            if (tid < 512) {
                const float* ep = p.embproj + (size_t)row * 2048 + tid;
                ep0 = ep[0]; ep1 = ep[512]; ep2 = ep[1024]; ep3 = ep[1536];
            }
        }

        // ---- LSTM1: g = Wpk1 @ [ctx||h1]  (emb term pre-folded into embproj) ----
        gemv_mfma<8, 20>(p.Wpk1, sh.xc1, sh.g, wv, lane);
        __syncthreads();
        if (tid < 512) {
            float gi = sigm(sh.g[tid] + ep0);
            float gf = sigm(sh.g[512 + tid] + ep1);
            float gg = tanh_(sh.g[1024 + tid] + ep2);
            float go = sigm(sh.g[1536 + tid] + ep3);
            float c = gf * sh.c1[tid] + gi * gg;
            sh.c1[tid] = c;
            unsigned short hb = f2b(go * tanh_(c));
            sh.xc1[128 + tid] = hb;   // h1 for next step
            sh.xc2[tid] = hb;         // h1 for LSTM2 now
        }
        __syncthreads();

        // ---- LSTM2 ----
        gemv_mfma<8, 32>(p.Wpk2, sh.xc2, sh.g, wv, lane);
        __syncthreads();
        if (tid < 512) {
            float gi = sigm(sh.g[tid] + sh.b2[tid]);
            float gf = sigm(sh.g[512 + tid] + sh.b2[512 + tid]);
            float gg = tanh_(sh.g[1024 + tid] + sh.b2[1024 + tid]);
            float go = sigm(sh.g[1536 + tid] + sh.b2[1536 + tid]);
            float c = gf * sh.c2[tid] + gi * gg;
            sh.c2[tid] = c;
            unsigned short hb = f2b(go * tanh_(c));
            sh.xc2[512 + tid] = hb;   // h2 for next step
            sh.xc3[tid] = hb;         // h2 for LSTM3 now
        }
        __syncthreads();

        // ---- LSTM3 ----
        gemv_mfma<2, 20>(p.Wpk3, sh.xc3, sh.g, wv, lane);
        __syncthreads();
        if (tid < 128) {
            float gi = sigm(sh.g[tid] + sh.b3[tid]);
            float gf = sigm(sh.g[128 + tid] + sh.b3[128 + tid]);
            float gg = tanh_(sh.g[256 + tid] + sh.b3[256 + tid]);
            float go = sigm(sh.g[384 + tid] + sh.b3[384 + tid]);
            float c = gf * sh.c3[tid] + gi * gg;
            sh.c3[tid] = c;
            float h = go * tanh_(c);
            sh.h3s[tid] = h;
            sh.xc3[512 + tid] = f2b(h);   // h3 for next step
        }
        __syncthreads();

        // ---- attention energies: thread owns t = tid, tid+1024 ----
        float e2[2];
        const unsigned short* kb = p.keyB + (size_t)n * T_ * KS_;
#pragma unroll
        for (int i = 0; i < 2; i++) {
            int t = tid + i * 1024;
            float e = -1e30f;
            if (t < len) {
                const unsigned short* kr = kb + (size_t)t * KS_;
                const float4v* hv = (const float4v*)sh.h3s;
                float s = 0.f;
#pragma unroll
                for (int kk = 0; kk < 16; kk++)
                    s += dot8(*(const short8*)(kr + kk * 8), hv[2 * kk], hv[2 * kk + 1]);
                e = s;
            }
            e2[i] = e;
        }
        float mloc = wredmax(fmaxf(e2[0], e2[1]));
        if (lane == 0) sh.red[wv] = mloc;
        __syncthreads();
        if (tid == 0) {
            float M = sh.red[0];
            for (int i = 1; i < 16; i++) M = fmaxf(M, sh.red[i]);
            sh.red[16] = M;
        }
        __syncthreads();
        const float M = sh.red[16];
        float pp[2]; float ps = 0.f;
#pragma unroll
        for (int i = 0; i < 2; i++) {
            int t = tid + i * 1024;
            float v = (t < len) ? __expf(e2[i] - M) : 0.f;
            pp[i] = v; ps += v;
            sh.att[t] = v;
        }
        ps = wredsum(ps);
        if (lane == 0) sh.red[wv] = ps;
        __syncthreads();
        if (tid == 0) {
            float s = 0.f;
            for (int i = 0; i < 16; i++) s += sh.red[i];
            sh.red[16] = 1.0f / s;
        }
        __syncthreads();
        const float rL = sh.red[16];
        // normalized attention to output (masked region pre-zeroed by memset)
#pragma unroll
        for (int i = 0; i < 2; i++) {
            int t = tid + i * 1024;
            if (t < len) attnout[(size_t)l * T_ + t] = pp[i] * rL;
        }
        // ---- ctx[e] = (sum_t p[t]*values[n][t][e]) * rL ----
        if (tid < 512) {
            const int tg = tid >> 4, e8 = tid & 15;
            float a8[8] = {0, 0, 0, 0, 0, 0, 0, 0};
            const unsigned short* vb = p.valB + (size_t)n * T_ * KS_ + e8 * 8;
            for (int t = tg; t < len; t += 32) {
                float w = sh.att[t];
                short8 v8 = *(const short8*)(vb + (size_t)t * KS_);
                a8[0] += w * b2f((unsigned short)v8[0]);
                a8[1] += w * b2f((unsigned short)v8[1]);
                a8[2] += w * b2f((unsigned short)v8[2]);
                a8[3] += w * b2f((unsigned short)v8[3]);
                a8[4] += w * b2f((unsigned short)v8[4]);
                a8[5] += w * b2f((unsigned short)v8[5]);
                a8[6] += w * b2f((unsigned short)v8[6]);
                a8[7] += w * b2f((unsigned short)v8[7]);
            }
#pragma unroll
            for (int j = 0; j < 8; j++) sh.ctxp[tg][e8 * 8 + j] = a8[j];
        }
        __syncthreads();
        if (tid < 128) {
            float s = 0.f;
#pragma unroll 8
            for (int g2 = 0; g2 < 32; g2++) s += sh.ctxp[g2][tid];
            s *= rL;
            sh.ctxf[tid] = s;
            sh.xc1[tid] = f2b(s);     // ctx -> next step's LSTM1 input
        }
        __syncthreads();
        // ---- logits = [h3||ctx] @ emb_W^T + b_out (fp32 for accuracy) ----
        if (tid < V_ * 8) {
            const int v = tid >> 3, oc = tid & 7;
            const float* er = p.emb_W + (size_t)v * E_ + oc * 32;
            const float* src = (oc < 4) ? (sh.h3s + oc * 32) : (sh.ctxf + oc * 32 - 128);
            float s = 0.f;
#pragma unroll
            for (int j = 0; j < 32; j++) s += src[j] * er[j];
            sh.lsum[v][oc] = s;
        }
        __syncthreads();
        if (tid < V_) {
            float s = p.b_out[tid];
#pragma unroll
            for (int j = 0; j < 8; j++) s += sh.lsum[tid][j];
            p.out[((size_t)n * L_ + l) * V_ + tid] = s;
        }
        // no barrier needed: next phase only writes sh.g / reads xc1, both quiesced above
    }
}

// ---------------- setup kernels ----------------
// Pack weights into MFMA-A-fragment order: [jt][kt][lane][8],
// elem = W[jt*16 + (lane&15)][kt*32 + (lane>>4)*8 + e]
__global__ void setup_weights(Params p)
{
    size_t stride = (size_t)gridDim.x * blockDim.x;
    size_t i0 = (size_t)blockIdx.x * blockDim.x + threadIdx.x;
    // Wpk1: 128 jt x 20 kt; K = [ctx(128 -> W_ih1 cols 256..383) || h1(512 -> W_hh1)]
    for (size_t i = i0; i < (size_t)128 * 20 * 512; i += stride) {
        int e = (int)(i & 7), lft = (int)((i >> 3) & 63);
        int kt = (int)((i >> 9) % 20u), jt = (int)((i >> 9) / 20u);
        int j = jt * 16 + (lft & 15);
        int k = kt * 32 + ((lft >> 4) << 3) + e;
        float v = (k < 128) ? p.W_ih1[(size_t)j * 384 + 256 + k]
                            : p.W_hh1[(size_t)j * 512 + (k - 128)];
        p.Wpk1[i] = f2b(v);
    }
    // Wpk2: 128 jt x 32 kt; K = [h1(512 -> W_ih2) || h2(512 -> W_hh2)]
    for (size_t i = i0; i < (size_t)128 * 32 * 512; i += stride) {
        int e = (int)(i & 7), lft = (int)((i >> 3) & 63);
        int kt = (int)((i >> 9) & 31), jt = (int)(i >> 14);
        int j = jt * 16 + (lft & 15);
        int k = kt * 32 + ((lft >> 4) << 3) + e;
        float v = (k < 512) ? p.W_ih2[(size_t)j * 512 + k]
                            : p.W_hh2[(size_t)j * 512 + (k - 512)];
        p.Wpk2[i] = f2b(v);
    }
    // Wpk3: 32 jt x 20 kt; K = [h2(512 -> W_ih3) || h3(128 -> W_hh3)]
    for (size_t i = i0; i < (size_t)32 * 20 * 512; i += stride) {
        int e = (int)(i & 7), lft = (int)((i >> 3) & 63);
        int kt = (int)((i >> 9) % 20u), jt = (int)((i >> 9) / 20u);
        int j = jt * 16 + (lft & 15);
        int k = kt * 32 + ((lft >> 4) << 3) + e;
        float v = (k < 512) ? p.W_ih3[(size_t)j * 512 + k]
                            : p.W_hh3[(size_t)j * 128 + (k - 512)];
        p.Wpk3[i] = f2b(v);
    }
    for (size_t i = i0; i < 2048; i += stride) p.b2[i] = p.b_ih2[i] + p.b_hh2[i];
    for (size_t i = i0; i < 512; i += stride) p.b3[i] = p.b_ih3[i] + p.b_hh3[i];
}

// embproj[c][j] = sum_k emb_W[c][k] * W_ih1[j][k] + b_ih1[j] + b_hh1[j]   (f32, exact)
__global__ void setup_embproj(Params p)
{
    int idx = blockIdx.x * blockDim.x + threadIdx.x;   // 35*2048 = 71680
    if (idx >= V_ * 2048) return;
    int c = idx >> 11, j = idx & 2047;
    float s = p.b_ih1[j] + p.b_hh1[j];
    const float* er = p.emb_W + (size_t)c * E_;
    const float* wr = p.W_ih1 + (size_t)j * 384;
    for (int k = 0; k < 256; k++) s += er[k] * wr[k];
    p.embproj[idx] = s;
}

__global__ void setup_kv(Params p)
{
    size_t stride = (size_t)gridDim.x * blockDim.x;
    const size_t total = (size_t)T_ * N_ * KS_;
    for (size_t idx = (size_t)blockIdx.x * blockDim.x + threadIdx.x; idx < total; idx += stride) {
        int t = (int)(idx >> 13);          // / (64*128)
        int rem = (int)(idx & 8191);
        int n = rem >> 7, k = rem & 127;
        size_t dst = ((size_t)n * T_ + t) * KS_ + k;
        p.keyB[dst] = f2b(p.key[idx]);
        p.valB[dst] = f2b(p.values[idx]);
    }
}

// ---------------- host ----------------
extern "C" void kernel_launch(void* const* d_in, const int* in_sizes, int n_in,
                              void* d_out, int out_size, void* d_ws, size_t ws_size,
                              hipStream_t stream)
{
    (void)in_sizes; (void)n_in; (void)out_size; (void)ws_size;
    Params p;
    p.key    = (const float*)d_in[0];
    p.values = (const float*)d_in[1];
    p.x_lens = (const int*)d_in[2];
    p.text   = (const int*)d_in[3];
    p.emb_W  = (const float*)d_in[4];
    p.W_ih1  = (const float*)d_in[5];
    p.W_hh1  = (const float*)d_in[6];
    p.b_ih1  = (const float*)d_in[7];
    p.b_hh1  = (const float*)d_in[8];
    p.W_ih2  = (const float*)d_in[9];
    p.W_hh2  = (const float*)d_in[10];
    p.b_ih2  = (const float*)d_in[11];
    p.b_hh2  = (const float*)d_in[12];
    p.W_ih3  = (const float*)d_in[13];
    p.W_hh3  = (const float*)d_in[14];
    p.b_ih3  = (const float*)d_in[15];
    p.b_hh3  = (const float*)d_in[16];
    p.b_out  = (const float*)d_in[17];
    p.out    = (float*)d_out;

    char* w = (char*)d_ws;
    auto alloc = [&](size_t bytes) -> char* {
        char* r = w;
        w += (bytes + 255) & ~(size_t)255;
        return r;
    };
    p.Wpk1    = (unsigned short*)alloc((size_t)128 * 20 * 512 * 2);
    p.Wpk2    = (unsigned short*)alloc((size_t)128 * 32 * 512 * 2);
    p.Wpk3    = (unsigned short*)alloc((size_t)32 * 20 * 512 * 2);
    p.embproj = (float*)alloc((size_t)V_ * 2048 * 4);
    p.b2      = (float*)alloc(2048 * 4);
    p.b3      = (float*)alloc(512 * 4);
    p.keyB    = (unsigned short*)alloc((size_t)16777216 * 2);
    p.valB    = (unsigned short*)alloc((size_t)16777216 * 2);

    // zero the att output region (masked slots must stay exactly 0)
    hipMemsetAsync((char*)d_out + (size_t)N_ * L_ * V_ * 4, 0,
                   (size_t)N_ * L_ * T_ * 4, stream);

    setup_weights<<<dim3(256), dim3(256), 0, stream>>>(p);
    setup_embproj<<<dim3(280), dim3(256), 0, stream>>>(p);
    setup_kv<<<dim3(2048), dim3(256), 0, stream>>>(p);

    // 64 independent WGs (one per batch element), plain launch, zero grid syncs
    decoder_main<<<dim3(64), dim3(1024), 0, stream>>>(p);
}

// Round 2
// 32427.228 us; speedup vs baseline: 2.9194x; 2.9194x over previous
//
#include <hip/hip_runtime.h>
#include <cstdint>
#include <cstddef>

#define T_ 2048
#define N_ 64
#define L_ 300
#define V_ 35
#define E_ 256
#define H_ 512
#define KS_ 128

typedef __attribute__((ext_vector_type(8))) short short8;
typedef __attribute__((ext_vector_type(4))) float float4v;

struct Params {
    // inputs (setup_inputs order)
    const float *key, *values;
    const int *x_lens, *text;
    const float *emb_W;
    const float *W_ih1, *W_hh1, *b_ih1, *b_hh1;
    const float *W_ih2, *W_hh2, *b_ih2, *b_hh2;
    const float *W_ih3, *W_hh3, *b_ih3, *b_hh3;
    const float *b_out;
    // workspace
    unsigned short *W1cat;   // [2048][640]  bf16, K = [ctx(128)||h1(512)]
    unsigned short *W2cat;   // [2048][1024] bf16, K = [h1(512)||h2prev(512)]
    unsigned short *Wih3b;   // [512][512]
    unsigned short *Whh3b;   // [512][128]
    float *embproj;          // [V][2048] = emb_W@W_ih1[:, :256]^T + b_ih1 + b_hh1
    float *b2, *b3;
    unsigned short *keyB, *valB;   // [n][t][k] bf16
    unsigned int *flag;            // barrier counter
    float *c1, *c2, *c3, *h3f;
    unsigned int *h1u0, *h1u1, *h2u0, *h2u1;  // [64][256] uint (2 bf16 each)
    unsigned int *x1u;                        // [64][64]  uint (ctx, 128 bf16)
    float *out;
};

__device__ __forceinline__ float b2f(unsigned short u) {
    unsigned int i = ((unsigned int)u) << 16;
    float f; __builtin_memcpy(&f, &i, 4); return f;
}
__device__ __forceinline__ unsigned short f2b(float f) {
    unsigned int i; __builtin_memcpy(&i, &f, 4);
    i += 0x7FFFu + ((i >> 16) & 1u);
    return (unsigned short)(i >> 16);
}
__device__ __forceinline__ float sigm(float x) { return 1.0f / (1.0f + __expf(-x)); }
__device__ __forceinline__ float tanh_(float x) {
    float e = __expf(2.0f * x);
    return 1.0f - 2.0f / (e + 1.0f);
}
__device__ __forceinline__ float wredmax(float v) {
#pragma unroll
    for (int o = 32; o > 0; o >>= 1) v = fmaxf(v, __shfl_down(v, o));
    return v;
}
__device__ __forceinline__ float wredsum(float v) {
#pragma unroll
    for (int o = 32; o > 0; o >>= 1) v += __shfl_down(v, o);
    return v;
}
__device__ __forceinline__ float dot8(short8 w8, float4v a, float4v b) {
    return b2f((unsigned short)w8[0]) * a[0] + b2f((unsigned short)w8[1]) * a[1]
         + b2f((unsigned short)w8[2]) * a[2] + b2f((unsigned short)w8[3]) * a[3]
         + b2f((unsigned short)w8[4]) * b[0] + b2f((unsigned short)w8[5]) * b[1]
         + b2f((unsigned short)w8[6]) * b[2] + b2f((unsigned short)w8[7]) * b[3];
}

// device-coherent (agent-scope, L2-bypassing) exchange primitives
__device__ __forceinline__ unsigned int cohLd(const unsigned int* p) {
    return __hip_atomic_load(p, __ATOMIC_RELAXED, __HIP_MEMORY_SCOPE_AGENT);
}
__device__ __forceinline__ void cohSt(unsigned int* p, unsigned int v) {
    __hip_atomic_store(p, v, __ATOMIC_RELAXED, __HIP_MEMORY_SCOPE_AGENT);
}

// Lightweight grid barrier: release fence (writes back dirty L2; does NOT
// invalidate clean lines -> weights stay L2-hot) + relaxed counter.
// All cross-WG payloads use cohLd/cohSt, so no acquire-invalidate is needed.
__device__ __forceinline__ void gbar(unsigned int* flag, unsigned int target, int tid) {
    __builtin_amdgcn_fence(__ATOMIC_RELEASE, "agent");
    __syncthreads();   // all waves drain vmcnt before s_barrier
    if (tid == 0) {
        __hip_atomic_fetch_add(flag, 1u, __ATOMIC_RELAXED, __HIP_MEMORY_SCOPE_AGENT);
        while (__hip_atomic_load(flag, __ATOMIC_RELAXED, __HIP_MEMORY_SCOPE_AGENT) < target)
            __builtin_amdgcn_s_sleep(2);
    }
    __syncthreads();
}

struct SharedD {
    float h2r[512];
    float h3p[128];
    float g3[512];
    float h3s[128];
    float att[2048];
    float ctxp[32][129];
    float ctxf[128];
    float red[32];
    float lsum[V_][8];
};
struct SharedAB {
    unsigned short xs[16][1032];   // staged A rows [16][K], K<=1024, +8 pad (row 2064B, 16B-aligned)
    float gld[2][4][16][16];       // gate exchange
};
union SharedU { SharedAB ab; SharedD d; };

// Batched GEMM tile: WG w handles m-tile mt=w&3 (16 batch rows), hidden-col pair ktp=w>>2.
// A rows come from LDS-staged xs (row stride 1032 shorts), B = weight cols (global, L2-hot).
template <int KX>
__device__ __forceinline__ void lstm_gemm(
    int wg, int tid,
    const unsigned short* xs,
    const unsigned short* __restrict__ W,   // [2048][KX]
    float (*gld)[4][16][16])
{
    const int lane = tid & 63, wv = tid >> 6;
    const int q = lane >> 4, l15 = lane & 15;
    const int ktp = wg >> 2;
    const int ktw = 2 * ktp + (wv & 1), tt = wv >> 1;   // tt = gate 0..3 (i,f,g,o)
    const int col = tt * H_ + ktw * 16 + l15;
    float4v acc = {0.f, 0.f, 0.f, 0.f};
    const unsigned short* ar = xs + l15 * 1032 + q * 8;
    const unsigned short* br = W + (size_t)col * KX + q * 8;
#pragma unroll
    for (int k0 = 0; k0 < KX; k0 += 32)
        acc = __builtin_amdgcn_mfma_f32_16x16x32_bf16(
            *(const short8*)(ar + k0), *(const short8*)(br + k0), acc, 0, 0, 0);
    // lane holds D[row=q*4+r][col=l15]; stash as [kt-sub][gate][kcol][mrow]
#pragma unroll
    for (int r = 0; r < 4; r++) gld[wv & 1][tt][l15][q * 4 + r] = acc[r];
}

__global__ __launch_bounds__(512) void decoder_main(Params p)
{
    __shared__ SharedU sm;
    const int wg = blockIdx.x;     // 0..63
    const int tid = threadIdx.x;   // 0..511
    const int lane = tid & 63, wv = tid >> 6;
    const int mt = wg & 3, ktp = wg >> 2;
    const int n = wg;
    const int len = p.x_lens[n];
    float* const attnout = p.out + (size_t)N_ * L_ * V_ + (size_t)n * L_ * T_;
    unsigned int tgt = 0;

    for (int l = 0; l < L_; ++l) {
        const unsigned int* h1prev = (l & 1) ? p.h1u1 : p.h1u0;
        unsigned int* h1cur        = (l & 1) ? p.h1u0 : p.h1u1;
        const unsigned int* h2prev = (l & 1) ? p.h2u1 : p.h2u0;
        unsigned int* h2cur        = (l & 1) ? p.h2u0 : p.h2u1;

        // ===== Phase A: LSTM1, K = [ctx(128) || h1prev(512)]; emb folded into embproj =====
        {
            unsigned int* xsu = (unsigned int*)&sm.ab.xs[0][0];
#pragma unroll
            for (int i = 0; i < 10; i++) {            // 16 rows x 320 uints
                int idx = tid + i * 512;
                int r = idx / 320, c = idx - r * 320;
                int nr = mt * 16 + r;
                unsigned int u = (c < 64) ? cohLd(p.x1u + nr * 64 + c)
                                          : cohLd(h1prev + nr * 256 + (c - 64));
                xsu[r * 516 + c] = u;
            }
        }
        __syncthreads();
        lstm_gemm<640>(wg, tid, &sm.ab.xs[0][0], p.W1cat, sm.ab.gld);
        __syncthreads();
        {
            const int kt2 = tid >> 8, kk = (tid >> 4) & 15, mm = tid & 15;
            const int kg = (2 * ktp + kt2) * 16 + kk;
            const int m2 = mt * 16 + mm;
            const float* eb = p.embproj + (size_t)p.text[m2 * L_ + l] * 2048;
            float gi = sm.ab.gld[kt2][0][kk][mm] + eb[kg];
            float gf = sm.ab.gld[kt2][1][kk][mm] + eb[512 + kg];
            float gg = sm.ab.gld[kt2][2][kk][mm] + eb[1024 + kg];
            float go = sm.ab.gld[kt2][3][kk][mm] + eb[1536 + kg];
            const size_t ix = (size_t)m2 * H_ + kg;
            float c = sigm(gf) * p.c1[ix] + sigm(gi) * tanh_(gg);
            p.c1[ix] = c;
            unsigned int hb = (unsigned int)f2b(sigm(go) * tanh_(c));
            unsigned int ob = (unsigned int)__shfl_xor((int)hb, 16);  // partner: kk^1
            if (!(kk & 1)) cohSt(h1cur + m2 * 256 + (kg >> 1), hb | (ob << 16));
        }
        tgt += 64; gbar(p.flag, tgt, tid);

        // ===== Phase B: LSTM2, K = [h1(512) || h2prev(512)] =====
        {
            unsigned int* xsu = (unsigned int*)&sm.ab.xs[0][0];
#pragma unroll
            for (int i = 0; i < 16; i++) {            // 16 rows x 512 uints
                int idx = tid + i * 512;
                int r = idx >> 9, c = idx & 511;
                int nr = mt * 16 + r;
                unsigned int u = (c < 256) ? cohLd(h1cur + nr * 256 + c)
                                           : cohLd(h2prev + nr * 256 + (c - 256));
                xsu[r * 516 + c] = u;
            }
        }
        __syncthreads();
        lstm_gemm<1024>(wg, tid, &sm.ab.xs[0][0], p.W2cat, sm.ab.gld);
        __syncthreads();
        {
            const int kt2 = tid >> 8, kk = (tid >> 4) & 15, mm = tid & 15;
            const int kg = (2 * ktp + kt2) * 16 + kk;
            const int m2 = mt * 16 + mm;
            float gi = sm.ab.gld[kt2][0][kk][mm] + p.b2[kg];
            float gf = sm.ab.gld[kt2][1][kk][mm] + p.b2[512 + kg];
            float gg = sm.ab.gld[kt2][2][kk][mm] + p.b2[1024 + kg];
            float go = sm.ab.gld[kt2][3][kk][mm] + p.b2[1536 + kg];
            const size_t ix = (size_t)m2 * H_ + kg;
            float c = sigm(gf) * p.c2[ix] + sigm(gi) * tanh_(gg);
            p.c2[ix] = c;
            unsigned int hb = (unsigned int)f2b(sigm(go) * tanh_(c));
            unsigned int ob = (unsigned int)__shfl_xor((int)hb, 16);
            if (!(kk & 1)) cohSt(h2cur + m2 * 256 + (kg >> 1), hb | (ob << 16));
        }
        tgt += 64; gbar(p.flag, tgt, tid);

        // ===== Phase D: per-n LSTM3 + attention + logits (WG n) =====
        {
            SharedD& sd = sm.d;
            // stage h2 (this step, coherent) and h3prev (WG-private)
            if (tid < 256) {
                unsigned int u = cohLd(h2cur + n * 256 + tid);
                sd.h2r[2 * tid]     = b2f((unsigned short)(u & 0xffffu));
                sd.h2r[2 * tid + 1] = b2f((unsigned short)(u >> 16));
            }
            if (tid < KS_) sd.h3p[tid] = p.h3f[n * KS_ + tid];
            __syncthreads();

            // LSTM3 gate pre-activations: thread = gate column (512)
            {
                float acc = p.b3[tid];
                const unsigned short* wr = p.Wih3b + (size_t)tid * H_;
#pragma unroll 4
                for (int k0 = 0; k0 < H_; k0 += 8) {
                    short8 w8 = *(const short8*)(wr + k0);
                    const float4v* hv = (const float4v*)(sd.h2r + k0);
                    acc += dot8(w8, hv[0], hv[1]);
                }
                const unsigned short* wr2 = p.Whh3b + (size_t)tid * KS_;
#pragma unroll 4
                for (int k0 = 0; k0 < KS_; k0 += 8) {
                    short8 w8 = *(const short8*)(wr2 + k0);
                    const float4v* hv = (const float4v*)(sd.h3p + k0);
                    acc += dot8(w8, hv[0], hv[1]);
                }
                sd.g3[tid] = acc;
            }
            __syncthreads();
            if (tid < KS_) {
                float gi = sigm(sd.g3[tid]);
                float gf = sigm(sd.g3[KS_ + tid]);
                float gg = tanh_(sd.g3[2 * KS_ + tid]);
                float go = sigm(sd.g3[3 * KS_ + tid]);
                float c = gf * p.c3[n * KS_ + tid] + gi * gg;
                p.c3[n * KS_ + tid] = c;
                float h = go * tanh_(c);
                sd.h3s[tid] = h;
                p.h3f[n * KS_ + tid] = h;
            }
            __syncthreads();

            // energies: thread owns t = tid + 512*i
            float e4[4];
            const unsigned short* kbase = p.keyB + (size_t)n * T_ * KS_;
#pragma unroll
            for (int i = 0; i < 4; i++) {
                int t = tid + 512 * i;
                float e = -1e30f;
                if (t < len) {
                    const unsigned short* kr = kbase + (size_t)t * KS_;
                    const float4v* hv = (const float4v*)sd.h3s;
                    float s = 0.f;
#pragma unroll
                    for (int kk = 0; kk < 16; kk++)
                        s += dot8(*(const short8*)(kr + kk * 8), hv[2 * kk], hv[2 * kk + 1]);
                    e = s;
                }
                e4[i] = e;
            }
            float mloc = fmaxf(fmaxf(e4[0], e4[1]), fmaxf(e4[2], e4[3]));
            mloc = wredmax(mloc);
            if (lane == 0) sd.red[wv] = mloc;
            __syncthreads();
            if (tid == 0) {
                float M = sd.red[0];
                for (int i = 1; i < 8; i++) M = fmaxf(M, sd.red[i]);
                sd.red[16] = M;
            }
            __syncthreads();
            const float M = sd.red[16];
            float pp[4]; float ps = 0.f;
#pragma unroll
            for (int i = 0; i < 4; i++) {
                int t = tid + 512 * i;
                float v = (t < len) ? __expf(e4[i] - M) : 0.f;
                pp[i] = v; ps += v;
                sd.att[t] = v;
            }
            ps = wredsum(ps);
            if (lane == 0) sd.red[wv] = ps;
            __syncthreads();
            if (tid == 0) {
                float s = 0.f;
                for (int i = 0; i < 8; i++) s += sd.red[i];
                sd.red[17] = 1.0f / s;
            }
            __syncthreads();
            const float rL = sd.red[17];
            {
                float* ao = attnout + (size_t)l * T_;
#pragma unroll
                for (int i = 0; i < 4; i++) {
                    int t = tid + 512 * i;
                    if (t < len) ao[t] = pp[i] * rL;
                }
            }
            // ctx[e] = (sum_t p[t]*values[n][t][e]) * rL
            {
                const int tg = tid >> 4, e8 = tid & 15;
                float a8[8] = {0, 0, 0, 0, 0, 0, 0, 0};
                const unsigned short* vbase = p.valB + (size_t)n * T_ * KS_ + e8 * 8;
                for (int t = tg; t < len; t += 32) {
                    float w = sd.att[t];
                    short8 v8 = *(const short8*)(vbase + (size_t)t * KS_);
                    a8[0] += w * b2f((unsigned short)v8[0]);
                    a8[1] += w * b2f((unsigned short)v8[1]);
                    a8[2] += w * b2f((unsigned short)v8[2]);
                    a8[3] += w * b2f((unsigned short)v8[3]);
                    a8[4] += w * b2f((unsigned short)v8[4]);
                    a8[5] += w * b2f((unsigned short)v8[5]);
                    a8[6] += w * b2f((unsigned short)v8[6]);
                    a8[7] += w * b2f((unsigned short)v8[7]);
                }
#pragma unroll
                for (int j = 0; j < 8; j++) sd.ctxp[tg][e8 * 8 + j] = a8[j];
            }
            __syncthreads();
            if (tid < KS_) {
                float s = 0.f;
#pragma unroll 8
                for (int g2 = 0; g2 < 32; g2++) s += sd.ctxp[g2][tid];
                s *= rL;
                sd.ctxf[tid] = s;
                unsigned int cb = (unsigned int)f2b(s);
                unsigned int ob = (unsigned int)__shfl_xor((int)cb, 1);
                if (!(tid & 1)) cohSt(p.x1u + n * 64 + (tid >> 1), cb | (ob << 16));
            }
            __syncthreads();
            // logits = [h3||ctx] @ emb_W^T + b_out (fp32)
            if (tid < V_ * 8) {
                const int v = tid >> 3, oc = tid & 7;
                const float* er = p.emb_W + (size_t)v * E_ + oc * 32;
                const float* src = (oc < 4) ? (sd.h3s + oc * 32) : (sd.ctxf + oc * 32 - 128);
                float s = 0.f;
#pragma unroll
                for (int j = 0; j < 32; j++) s += src[j] * er[j];
                sd.lsum[v][oc] = s;
            }
            __syncthreads();
            if (tid < V_) {
                float s = p.b_out[tid];
#pragma unroll
                for (int j = 0; j < 8; j++) s += sd.lsum[tid][j];
                p.out[((size_t)n * L_ + l) * V_ + tid] = s;
            }
        }
        tgt += 64; gbar(p.flag, tgt, tid);
    }
}

// ---------------- setup kernels ----------------
__global__ void setup_weights(Params p)
{
    size_t stride = (size_t)gridDim.x * blockDim.x;
    size_t i0 = (size_t)blockIdx.x * blockDim.x + threadIdx.x;
    // W1cat [j][640]: k<128 -> W_ih1[j][256+k] (ctx), else W_hh1[j][k-128]
    for (size_t i = i0; i < (size_t)2048 * 640; i += stride) {
        int j = (int)(i / 640), k = (int)(i - (size_t)j * 640);
        float v = (k < 128) ? p.W_ih1[(size_t)j * 384 + 256 + k]
                            : p.W_hh1[(size_t)j * 512 + (k - 128)];
        p.W1cat[i] = f2b(v);
    }
    // W2cat [j][1024]: k<512 -> W_ih2[j][k], else W_hh2[j][k-512]
    for (size_t i = i0; i < (size_t)2048 * 1024; i += stride) {
        int j = (int)(i >> 10), k = (int)(i & 1023);
        float v = (k < 512) ? p.W_ih2[(size_t)j * 512 + k]
                            : p.W_hh2[(size_t)j * 512 + (k - 512)];
        p.W2cat[i] = f2b(v);
    }
    for (size_t i = i0; i < (size_t)512 * 512; i += stride) p.Wih3b[i] = f2b(p.W_ih3[i]);
    for (size_t i = i0; i < (size_t)512 * 128; i += stride) p.Whh3b[i] = f2b(p.W_hh3[i]);
    for (size_t i = i0; i < 2048; i += stride) p.b2[i] = p.b_ih2[i] + p.b_hh2[i];
    for (size_t i = i0; i < 512; i += stride) p.b3[i] = p.b_ih3[i] + p.b_hh3[i];
}

// embproj[c][j] = sum_k emb_W[c][k] * W_ih1[j][k] + b_ih1[j] + b_hh1[j]
__global__ void setup_embproj(Params p)
{
    int idx = blockIdx.x * blockDim.x + threadIdx.x;   // 35*2048
    if (idx >= V_ * 2048) return;
    int c = idx >> 11, j = idx & 2047;
    float s = p.b_ih1[j] + p.b_hh1[j];
    const float* er = p.emb_W + (size_t)c * E_;
    const float* wr = p.W_ih1 + (size_t)j * 384;
    for (int k = 0; k < 256; k++) s += er[k] * wr[k];
    p.embproj[idx] = s;
}

__global__ void setup_kv(Params p)
{
    size_t stride = (size_t)gridDim.x * blockDim.x;
    const size_t total = (size_t)T_ * N_ * KS_;
    for (size_t idx = (size_t)blockIdx.x * blockDim.x + threadIdx.x; idx < total; idx += stride) {
        int t = (int)(idx >> 13);
        int rem = (int)(idx & 8191);
        int n = rem >> 7, k = rem & 127;
        size_t dst = ((size_t)n * T_ + t) * KS_ + k;
        p.keyB[dst] = f2b(p.key[idx]);
        p.valB[dst] = f2b(p.values[idx]);
    }
}

// ---------------- host ----------------
extern "C" void kernel_launch(void* const* d_in, const int* in_sizes, int n_in,
                              void* d_out, int out_size, void* d_ws, size_t ws_size,
                              hipStream_t stream)
{
    (void)in_sizes; (void)n_in; (void)out_size; (void)ws_size;
    Params p;
    p.key    = (const float*)d_in[0];
    p.values = (const float*)d_in[1];
    p.x_lens = (const int*)d_in[2];
    p.text   = (const int*)d_in[3];
    p.emb_W  = (const float*)d_in[4];
    p.W_ih1  = (const float*)d_in[5];
    p.W_hh1  = (const float*)d_in[6];
    p.b_ih1  = (const float*)d_in[7];
    p.b_hh1  = (const float*)d_in[8];
    p.W_ih2  = (const float*)d_in[9];
    p.W_hh2  = (const float*)d_in[10];
    p.b_ih2  = (const float*)d_in[11];
    p.b_hh2  = (const float*)d_in[12];
    p.W_ih3  = (const float*)d_in[13];
    p.W_hh3  = (const float*)d_in[14];
    p.b_ih3  = (const float*)d_in[15];
    p.b_hh3  = (const float*)d_in[16];
    p.b_out  = (const float*)d_in[17];
    p.out    = (float*)d_out;

    char* w = (char*)d_ws;
    auto alloc = [&](size_t bytes) -> char* {
        char* r = w;
        w += (bytes + 255) & ~(size_t)255;
        return r;
    };
    p.W1cat   = (unsigned short*)alloc((size_t)2048 * 640 * 2);
    p.W2cat   = (unsigned short*)alloc((size_t)2048 * 1024 * 2);
    p.Wih3b   = (unsigned short*)alloc((size_t)512 * 512 * 2);
    p.Whh3b   = (unsigned short*)alloc((size_t)512 * 128 * 2);
    p.embproj = (float*)alloc((size_t)V_ * 2048 * 4);
    p.b2      = (float*)alloc(2048 * 4);
    p.b3      = (float*)alloc(512 * 4);
    p.keyB    = (unsigned short*)alloc((size_t)16777216 * 2);
    p.valB    = (unsigned short*)alloc((size_t)16777216 * 2);
    char* zstart = w;
    p.flag = (unsigned int*)alloc(256);
    p.c1   = (float*)alloc((size_t)N_ * H_ * 4);
    p.c2   = (float*)alloc((size_t)N_ * H_ * 4);
    p.c3   = (float*)alloc((size_t)N_ * KS_ * 4);
    p.h3f  = (float*)alloc((size_t)N_ * KS_ * 4);
    p.h1u0 = (unsigned int*)alloc((size_t)N_ * 256 * 4);
    p.h1u1 = (unsigned int*)alloc((size_t)N_ * 256 * 4);
    p.h2u0 = (unsigned int*)alloc((size_t)N_ * 256 * 4);
    p.h2u1 = (unsigned int*)alloc((size_t)N_ * 256 * 4);
    p.x1u  = (unsigned int*)alloc((size_t)N_ * 64 * 4);
    size_t zbytes = (size_t)(w - zstart);

    // zero barrier flag + all recurrent state; zero att output region (masked slots stay 0)
    hipMemsetAsync(zstart, 0, zbytes, stream);
    hipMemsetAsync((char*)d_out + (size_t)N_ * L_ * V_ * 4, 0,
                   (size_t)N_ * L_ * T_ * 4, stream);

    setup_weights<<<dim3(256), dim3(256), 0, stream>>>(p);
    setup_embproj<<<dim3(280), dim3(256), 0, stream>>>(p);
    setup_kv<<<dim3(2048), dim3(256), 0, stream>>>(p);

    // cooperative launch guarantees co-residency of all 64 WGs (required by gbar)
    void* args[] = { (void*)&p };
    hipLaunchCooperativeKernel((void*)decoder_main, dim3(64), dim3(512), args, 0, stream);
}